// Round 1
// baseline (3128.656 us; speedup 1.0000x reference)
//
#include <hip/hip_runtime.h>
#include <cstdint>

#define T 1024
#define H 2048
#define II 1408
#define E 32
#define TOPK 6
#define NGRP 4
#define GSZ 8
#define CAP 1024
#define CAPH 384
#define KP 72

typedef __attribute__((ext_vector_type(8))) short short8;
typedef __attribute__((ext_vector_type(4))) float f32x4;
typedef __attribute__((ext_vector_type(4))) unsigned short us4;

static __device__ __forceinline__ unsigned short f2bf(float f) {
    unsigned int u = __builtin_bit_cast(unsigned int, f);
    u += 0x7FFFu + ((u >> 16) & 1u);
    return (unsigned short)(u >> 16);
}

__global__ void prep_kernel(const float* __restrict__ x, unsigned short* __restrict__ xbf,
                            int* __restrict__ list, float* __restrict__ wts,
                            int* __restrict__ cnt) {
    int gid = blockIdx.x * blockDim.x + threadIdx.x;
    const int n4 = T * H / 4;
    if (gid < n4) {
        const float4 v = reinterpret_cast<const float4*>(x)[gid];
        us4 o;
        o.x = f2bf(v.x); o.y = f2bf(v.y); o.z = f2bf(v.z); o.w = f2bf(v.w);
        reinterpret_cast<us4*>(xbf)[gid] = o;
    }
    if (gid < T) { list[E * CAP + gid] = gid; wts[E * CAP + gid] = 1.0f; }
    if (gid < E + 1) cnt[gid] = (gid == E) ? T : 0;
}

__global__ __launch_bounds__(256) void router_kernel(
        const float* __restrict__ x, const float* __restrict__ gw,
        const float* __restrict__ bias, int* __restrict__ list,
        float* __restrict__ wts, int* __restrict__ cnt) {
    int t = blockIdx.x;
    int tid = threadIdx.x;
    int e = tid >> 3, p = tid & 7;
    const float4* xr = reinterpret_cast<const float4*>(x + (size_t)t * H);
    const float4* gr = reinterpret_cast<const float4*>(gw + (size_t)e * H);
    float part = 0.f;
    for (int q = 0; q < 64; ++q) {
        int idx = p * 64 + q;
        float4 a = xr[idx], b = gr[idx];
        part += a.x * b.x + a.y * b.y + a.z * b.z + a.w * b.w;
    }
    __shared__ float red[256];
    __shared__ float sc[E], sfc[E];
    red[tid] = part;
    __syncthreads();
    if (tid < E) {
        float s = 0.f;
        for (int j = 0; j < 8; ++j) s += red[tid * 8 + j];
        float sig = 1.f / (1.f + expf(-s));
        sc[tid] = sig;
        sfc[tid] = sig + bias[tid];
    }
    __syncthreads();
    if (tid == 0) {
        float gs[NGRP];
        for (int g = 0; g < NGRP; ++g) {
            float m1 = -INFINITY, m2 = -INFINITY;
            for (int j = 0; j < GSZ; ++j) {
                float v = sfc[g * GSZ + j];
                if (v > m1) { m2 = m1; m1 = v; }
                else if (v > m2) m2 = v;
            }
            gs[g] = m1 + m2;
        }
        int g1 = 0;
        for (int g = 1; g < NGRP; ++g) if (gs[g] > gs[g1]) g1 = g;
        int g2 = -1;
        for (int g = 0; g < NGRP; ++g) {
            if (g == g1) continue;
            if (g2 < 0 || gs[g] > gs[g2]) g2 = g;
        }
        int sel[TOPK];
        unsigned int usedmask = 0;
        float wsum = 0.f;
        for (int k = 0; k < TOPK; ++k) {
            float best = -INFINITY; int bi = -1;
            for (int ee = 0; ee < E; ++ee) {
                int g = ee >> 3;
                if (g != g1 && g != g2) continue;
                if (usedmask & (1u << ee)) continue;
                if (sfc[ee] > best) { best = sfc[ee]; bi = ee; }
            }
            usedmask |= (1u << bi);
            sel[k] = bi;
            wsum += sc[bi];
        }
        float fac = 2.5f / (wsum + 1e-20f);
        for (int k = 0; k < TOPK; ++k) {
            int ee = sel[k];
            int pos = atomicAdd(&cnt[ee], 1);
            list[ee * CAP + pos] = t;
            wts[ee * CAP + pos] = sc[ee] * fac;
        }
    }
}

// Pass A: h[pair, i] = silu(x @ Wg) * (x @ Wu), bf16 MFMA, K-outer so each
// weight element is fetched from HBM exactly once per call.
__global__ __launch_bounds__(256) void passA_kernel(
        const unsigned short* __restrict__ xbf,
        const float* __restrict__ wgate, const float* __restrict__ wup,
        const float* __restrict__ swgate, const float* __restrict__ swup,
        const int* __restrict__ list, const int* __restrict__ cnt,
        unsigned short* __restrict__ h) {
    int bx = blockIdx.x;
    int ve, start, end;
    if (bx < E) { ve = bx; start = 0; end = cnt[ve]; }
    else        { ve = E; start = (bx - E) * 256; end = start + 256; }
    if (start >= end) return;
    const float* G = (ve < E) ? wgate + (size_t)ve * H * II : swgate;
    const float* U = (ve < E) ? wup   + (size_t)ve * H * II : swup;
    int i0 = blockIdx.y * 64;
    int tid = threadIdx.x, wave = tid >> 6, lane = tid & 63;
    int lcol = lane & 15, lkg = lane >> 4;
    __shared__ unsigned short lG[64][KP];
    __shared__ unsigned short lU[64][KP];
    __shared__ int tokL[256];
    int slotbase = (ve < E) ? ve * CAPH : E * CAPH;
    for (int m0 = start; m0 < end; m0 += 256) {
        int msize = min(256, end - m0);
        tokL[tid] = (tid < msize) ? list[ve * CAP + m0 + tid] : 0;
        f32x4 accg[4][4] = {};
        f32x4 accu[4][4] = {};
        __syncthreads();
        bool wact = (wave * 64) < msize;
        for (int k0 = 0; k0 < H; k0 += 64) {
            #pragma unroll
            for (int r = 0; r < 4; ++r) {
                int kk = r * 16 + (tid >> 4);
                int ii = (tid & 15) * 4;
                const float4 g4 = *reinterpret_cast<const float4*>(&G[(size_t)(k0 + kk) * II + i0 + ii]);
                const float4 u4 = *reinterpret_cast<const float4*>(&U[(size_t)(k0 + kk) * II + i0 + ii]);
                lG[ii + 0][kk] = f2bf(g4.x); lG[ii + 1][kk] = f2bf(g4.y);
                lG[ii + 2][kk] = f2bf(g4.z); lG[ii + 3][kk] = f2bf(g4.w);
                lU[ii + 0][kk] = f2bf(u4.x); lU[ii + 1][kk] = f2bf(u4.y);
                lU[ii + 2][kk] = f2bf(u4.z); lU[ii + 3][kk] = f2bf(u4.w);
            }
            __syncthreads();
            if (wact) {
                #pragma unroll
                for (int s = 0; s < 2; ++s) {
                    short8 a[4];
                    #pragma unroll
                    for (int m = 0; m < 4; ++m) {
                        int row = wave * 64 + m * 16 + lcol;
                        int tok = tokL[row];
                        a[m] = *reinterpret_cast<const short8*>(
                            &xbf[(size_t)tok * H + k0 + s * 32 + lkg * 8]);
                    }
                    #pragma unroll
                    for (int n = 0; n < 4; ++n) {
                        const short8 bg = *reinterpret_cast<const short8*>(&lG[n * 16 + lcol][s * 32 + lkg * 8]);
                        const short8 bu = *reinterpret_cast<const short8*>(&lU[n * 16 + lcol][s * 32 + lkg * 8]);
                        #pragma unroll
                        for (int m = 0; m < 4; ++m) {
                            accg[m][n] = __builtin_amdgcn_mfma_f32_16x16x32_bf16(a[m], bg, accg[m][n], 0, 0, 0);
                            accu[m][n] = __builtin_amdgcn_mfma_f32_16x16x32_bf16(a[m], bu, accu[m][n], 0, 0, 0);
                        }
                    }
                }
            }
            __syncthreads();
        }
        if (wact) {
            for (int m = 0; m < 4; ++m)
                for (int n = 0; n < 4; ++n)
                    for (int r = 0; r < 4; ++r) {
                        int rowl = wave * 64 + m * 16 + lkg * 4 + r;
                        if (rowl >= msize) continue;
                        int pos = m0 + rowl;
                        if (ve < E && pos >= CAPH) continue;
                        float gv = accg[m][n][r], uv = accu[m][n][r];
                        float hv = gv / (1.f + expf(-gv)) * uv;
                        h[(size_t)(slotbase + pos) * II + i0 + n * 16 + lcol] = f2bf(hv);
                    }
        }
        __syncthreads();
    }
}

// Pass B: out[tok] += wt * (h @ Wdown)
__global__ __launch_bounds__(256) void passB_kernel(
        const unsigned short* __restrict__ h,
        const float* __restrict__ wdown, const float* __restrict__ swdown,
        const int* __restrict__ list, const float* __restrict__ wts,
        const int* __restrict__ cnt, float* __restrict__ out) {
    int bx = blockIdx.x;
    int ve, start, end;
    if (bx < E) { ve = bx; start = 0; end = cnt[ve]; }
    else        { ve = E; start = (bx - E) * 256; end = start + 256; }
    if (start >= end) return;
    const float* W = (ve < E) ? wdown + (size_t)ve * II * H : swdown;
    int n0 = blockIdx.y * 128;
    int tid = threadIdx.x, wave = tid >> 6, lane = tid & 63;
    int lcol = lane & 15, lkg = lane >> 4;
    __shared__ unsigned short lW[128][KP];
    __shared__ int tokL[256];
    __shared__ float wtL[256];
    int slotbase = (ve < E) ? ve * CAPH : E * CAPH;
    for (int m0 = start; m0 < end; m0 += 256) {
        int msize = min(256, end - m0);
        tokL[tid] = (tid < msize) ? list[ve * CAP + m0 + tid] : 0;
        wtL[tid]  = (tid < msize) ? wts[ve * CAP + m0 + tid] : 0.f;
        f32x4 acc[4][8] = {};
        __syncthreads();
        bool wact = (wave * 64) < msize;
        for (int k0 = 0; k0 < II; k0 += 64) {
            #pragma unroll
            for (int r = 0; r < 8; ++r) {
                int kk = r * 8 + (tid >> 5);
                int nn = (tid & 31) * 4;
                const float4 w4 = *reinterpret_cast<const float4*>(&W[(size_t)(k0 + kk) * H + n0 + nn]);
                lW[nn + 0][kk] = f2bf(w4.x); lW[nn + 1][kk] = f2bf(w4.y);
                lW[nn + 2][kk] = f2bf(w4.z); lW[nn + 3][kk] = f2bf(w4.w);
            }
            __syncthreads();
            if (wact) {
                #pragma unroll
                for (int s = 0; s < 2; ++s) {
                    short8 a[4];
                    #pragma unroll
                    for (int m = 0; m < 4; ++m) {
                        int rowl = wave * 64 + m * 16 + lcol;
                        int slot = slotbase + m0 + rowl;
                        a[m] = *reinterpret_cast<const short8*>(
                            &h[(size_t)slot * II + k0 + s * 32 + lkg * 8]);
                    }
                    #pragma unroll
                    for (int n = 0; n < 8; ++n) {
                        const short8 b = *reinterpret_cast<const short8*>(&lW[n * 16 + lcol][s * 32 + lkg * 8]);
                        #pragma unroll
                        for (int m = 0; m < 4; ++m)
                            acc[m][n] = __builtin_amdgcn_mfma_f32_16x16x32_bf16(a[m], b, acc[m][n], 0, 0, 0);
                    }
                }
            }
            __syncthreads();
        }
        if (wact) {
            for (int m = 0; m < 4; ++m)
                for (int n = 0; n < 8; ++n)
                    for (int r = 0; r < 4; ++r) {
                        int rowl = wave * 64 + m * 16 + lkg * 4 + r;
                        if (rowl >= msize) continue;
                        int tok = tokL[rowl];
                        float wv = wtL[rowl];
                        unsafeAtomicAdd(&out[(size_t)tok * H + n0 + n * 16 + lcol],
                                        acc[m][n][r] * wv);
                    }
        }
        __syncthreads();
    }
}

extern "C" void kernel_launch(void* const* d_in, const int* in_sizes, int n_in,
                              void* d_out, int out_size, void* d_ws, size_t ws_size,
                              hipStream_t stream) {
    const float* x       = (const float*)d_in[0];
    const float* gate_w  = (const float*)d_in[1];
    const float* e_bias  = (const float*)d_in[2];
    const float* w_gate  = (const float*)d_in[3];
    const float* w_up    = (const float*)d_in[4];
    const float* w_down  = (const float*)d_in[5];
    const float* sw_gate = (const float*)d_in[6];
    const float* sw_up   = (const float*)d_in[7];
    const float* sw_down = (const float*)d_in[8];
    float* out = (float*)d_out;

    char* ws = (char*)d_ws;
    unsigned short* xbf = (unsigned short*)ws;                       // 4 MB
    int*   list = (int*)(ws + 4194304);                              // 132 KB
    float* wts  = (float*)(ws + 4194304 + 135168);                   // 132 KB
    int*   cnt  = (int*)(ws + 4194304 + 2 * 135168);                 // 256 B
    unsigned short* h = (unsigned short*)(ws + 4194304 + 2 * 135168 + 256); // ~37.5 MB

    hipMemsetAsync(d_out, 0, (size_t)T * H * sizeof(float), stream);
    prep_kernel<<<dim3(2048), dim3(256), 0, stream>>>(x, xbf, list, wts, cnt);
    router_kernel<<<dim3(T), dim3(256), 0, stream>>>(x, gate_w, e_bias, list, wts, cnt);
    passA_kernel<<<dim3(36, 22), dim3(256), 0, stream>>>(xbf, w_gate, w_up, sw_gate, sw_up, list, cnt, h);
    passB_kernel<<<dim3(36, 16), dim3(256), 0, stream>>>(h, w_down, sw_down, list, wts, cnt, out);
}

// Round 2
// 826.183 us; speedup vs baseline: 3.7869x; 3.7869x over previous
//
#include <hip/hip_runtime.h>
#include <cstdint>

#define T 1024
#define H 2048
#define II 1408
#define E 32
#define TOPK 6
#define NGRP 4
#define GSZ 8
#define CAP 1024
#define CAPH 384
#define KP 72

typedef __attribute__((ext_vector_type(8))) short short8;
typedef __attribute__((ext_vector_type(4))) float f32x4;
typedef __attribute__((ext_vector_type(4))) unsigned short us4;

static __device__ __forceinline__ unsigned short f2bf(float f) {
    unsigned int u = __builtin_bit_cast(unsigned int, f);
    u += 0x7FFFu + ((u >> 16) & 1u);
    return (unsigned short)(u >> 16);
}

__global__ void prep_kernel(const float* __restrict__ x, unsigned short* __restrict__ xbf,
                            int* __restrict__ list, float* __restrict__ wts,
                            int* __restrict__ cnt) {
    int gid = blockIdx.x * blockDim.x + threadIdx.x;
    const int n4 = T * H / 4;
    if (gid < n4) {
        const float4 v = reinterpret_cast<const float4*>(x)[gid];
        us4 o;
        o.x = f2bf(v.x); o.y = f2bf(v.y); o.z = f2bf(v.z); o.w = f2bf(v.w);
        reinterpret_cast<us4*>(xbf)[gid] = o;
    }
    if (gid < T) { list[E * CAP + gid] = gid; wts[E * CAP + gid] = 1.0f; }
    if (gid < E + 1) cnt[gid] = (gid == E) ? T : 0;
}

__global__ __launch_bounds__(256) void router_kernel(
        const float* __restrict__ x, const float* __restrict__ gw,
        const float* __restrict__ bias, int* __restrict__ list,
        float* __restrict__ wts, int* __restrict__ cnt) {
    int t = blockIdx.x;
    int tid = threadIdx.x;
    int e = tid >> 3, p = tid & 7;
    const float4* xr = reinterpret_cast<const float4*>(x + (size_t)t * H);
    const float4* gr = reinterpret_cast<const float4*>(gw + (size_t)e * H);
    float part = 0.f;
    for (int q = 0; q < 64; ++q) {
        int idx = p * 64 + q;
        float4 a = xr[idx], b = gr[idx];
        part += a.x * b.x + a.y * b.y + a.z * b.z + a.w * b.w;
    }
    __shared__ float red[256];
    __shared__ float sc[E], sfc[E];
    red[tid] = part;
    __syncthreads();
    if (tid < E) {
        float s = 0.f;
        for (int j = 0; j < 8; ++j) s += red[tid * 8 + j];
        float sig = 1.f / (1.f + expf(-s));
        sc[tid] = sig;
        sfc[tid] = sig + bias[tid];
    }
    __syncthreads();
    if (tid == 0) {
        float gs[NGRP];
        for (int g = 0; g < NGRP; ++g) {
            float m1 = -INFINITY, m2 = -INFINITY;
            for (int j = 0; j < GSZ; ++j) {
                float v = sfc[g * GSZ + j];
                if (v > m1) { m2 = m1; m1 = v; }
                else if (v > m2) m2 = v;
            }
            gs[g] = m1 + m2;
        }
        int g1 = 0;
        for (int g = 1; g < NGRP; ++g) if (gs[g] > gs[g1]) g1 = g;
        int g2 = -1;
        for (int g = 0; g < NGRP; ++g) {
            if (g == g1) continue;
            if (g2 < 0 || gs[g] > gs[g2]) g2 = g;
        }
        int sel[TOPK];
        unsigned int usedmask = 0;
        float wsum = 0.f;
        for (int k = 0; k < TOPK; ++k) {
            float best = -INFINITY; int bi = -1;
            for (int ee = 0; ee < E; ++ee) {
                int g = ee >> 3;
                if (g != g1 && g != g2) continue;
                if (usedmask & (1u << ee)) continue;
                if (sfc[ee] > best) { best = sfc[ee]; bi = ee; }
            }
            usedmask |= (1u << bi);
            sel[k] = bi;
            wsum += sc[bi];
        }
        float fac = 2.5f / (wsum + 1e-20f);
        for (int k = 0; k < TOPK; ++k) {
            int ee = sel[k];
            int pos = atomicAdd(&cnt[ee], 1);
            list[ee * CAP + pos] = t;
            wts[ee * CAP + pos] = sc[ee] * fac;
        }
    }
}

// Pass A: h[pair, i] = silu(x @ Wg) * (x @ Wu), bf16 MFMA, K-outer so each
// weight element is fetched from HBM exactly once per call.
__global__ __launch_bounds__(256) void passA_kernel(
        const unsigned short* __restrict__ xbf,
        const float* __restrict__ wgate, const float* __restrict__ wup,
        const float* __restrict__ swgate, const float* __restrict__ swup,
        const int* __restrict__ list, const int* __restrict__ cnt,
        unsigned short* __restrict__ h) {
    int bx = blockIdx.x;
    int ve, start, end;
    if (bx < E) { ve = bx; start = 0; end = cnt[ve]; }
    else        { ve = E; start = (bx - E) * 256; end = start + 256; }
    if (start >= end) return;
    const float* G = (ve < E) ? wgate + (size_t)ve * H * II : swgate;
    const float* U = (ve < E) ? wup   + (size_t)ve * H * II : swup;
    int i0 = blockIdx.y * 64;
    int tid = threadIdx.x, wave = tid >> 6, lane = tid & 63;
    int lcol = lane & 15, lkg = lane >> 4;
    __shared__ unsigned short lG[64][KP];
    __shared__ unsigned short lU[64][KP];
    __shared__ int tokL[256];
    int slotbase = (ve < E) ? ve * CAPH : E * CAPH;
    for (int m0 = start; m0 < end; m0 += 256) {
        int msize = min(256, end - m0);
        tokL[tid] = (tid < msize) ? list[ve * CAP + m0 + tid] : 0;
        f32x4 accg[4][4] = {};
        f32x4 accu[4][4] = {};
        __syncthreads();
        bool wact = (wave * 64) < msize;
        // hoist per-lane A-row pointers out of the K loop
        const unsigned short* xrow[4];
        #pragma unroll
        for (int m = 0; m < 4; ++m) {
            int row = wave * 64 + m * 16 + lcol;
            xrow[m] = xbf + (size_t)tokL[row] * H;
        }
        for (int k0 = 0; k0 < H; k0 += 64) {
            #pragma unroll
            for (int r = 0; r < 4; ++r) {
                int kk = r * 16 + (tid >> 4);
                int ii = (tid & 15) * 4;
                const float4 g4 = *reinterpret_cast<const float4*>(&G[(size_t)(k0 + kk) * II + i0 + ii]);
                const float4 u4 = *reinterpret_cast<const float4*>(&U[(size_t)(k0 + kk) * II + i0 + ii]);
                lG[ii + 0][kk] = f2bf(g4.x); lG[ii + 1][kk] = f2bf(g4.y);
                lG[ii + 2][kk] = f2bf(g4.z); lG[ii + 3][kk] = f2bf(g4.w);
                lU[ii + 0][kk] = f2bf(u4.x); lU[ii + 1][kk] = f2bf(u4.y);
                lU[ii + 2][kk] = f2bf(u4.z); lU[ii + 3][kk] = f2bf(u4.w);
            }
            __syncthreads();
            if (wact) {
                #pragma unroll
                for (int s = 0; s < 2; ++s) {
                    short8 a[4];
                    #pragma unroll
                    for (int m = 0; m < 4; ++m)
                        a[m] = *reinterpret_cast<const short8*>(&xrow[m][k0 + s * 32 + lkg * 8]);
                    #pragma unroll
                    for (int n = 0; n < 4; ++n) {
                        const short8 bg = *reinterpret_cast<const short8*>(&lG[n * 16 + lcol][s * 32 + lkg * 8]);
                        const short8 bu = *reinterpret_cast<const short8*>(&lU[n * 16 + lcol][s * 32 + lkg * 8]);
                        #pragma unroll
                        for (int m = 0; m < 4; ++m) {
                            accg[m][n] = __builtin_amdgcn_mfma_f32_16x16x32_bf16(a[m], bg, accg[m][n], 0, 0, 0);
                            accu[m][n] = __builtin_amdgcn_mfma_f32_16x16x32_bf16(a[m], bu, accu[m][n], 0, 0, 0);
                        }
                    }
                }
            }
            __syncthreads();
        }
        if (wact) {
            #pragma unroll
            for (int m = 0; m < 4; ++m)
                #pragma unroll
                for (int n = 0; n < 4; ++n)
                    #pragma unroll
                    for (int r = 0; r < 4; ++r) {
                        int rowl = wave * 64 + m * 16 + lkg * 4 + r;
                        int pos = m0 + rowl;
                        bool ok = (rowl < msize) && !(ve < E && pos >= CAPH);
                        float gv = accg[m][n][r], uv = accu[m][n][r];
                        float hv = gv / (1.f + expf(-gv)) * uv;
                        if (ok)
                            h[(size_t)(slotbase + pos) * II + i0 + n * 16 + lcol] = f2bf(hv);
                    }
        }
        __syncthreads();
    }
}

// Pass B: out[tok] += wt * (h @ Wdown)
__global__ __launch_bounds__(256) void passB_kernel(
        const unsigned short* __restrict__ h,
        const float* __restrict__ wdown, const float* __restrict__ swdown,
        const int* __restrict__ list, const float* __restrict__ wts,
        const int* __restrict__ cnt, float* __restrict__ out) {
    int bx = blockIdx.x;
    int ve, start, end;
    if (bx < E) { ve = bx; start = 0; end = cnt[ve]; }
    else        { ve = E; start = (bx - E) * 256; end = start + 256; }
    if (start >= end) return;
    const float* W = (ve < E) ? wdown + (size_t)ve * II * H : swdown;
    int n0 = blockIdx.y * 128;
    int tid = threadIdx.x, wave = tid >> 6, lane = tid & 63;
    int lcol = lane & 15, lkg = lane >> 4;
    __shared__ unsigned short lW[128][KP];
    __shared__ int tokL[256];
    __shared__ float wtL[256];
    int slotbase = (ve < E) ? ve * CAPH : E * CAPH;
    for (int m0 = start; m0 < end; m0 += 256) {
        int msize = min(256, end - m0);
        tokL[tid] = (tid < msize) ? list[ve * CAP + m0 + tid] : 0;
        wtL[tid]  = (tid < msize) ? wts[ve * CAP + m0 + tid] : 0.f;
        f32x4 acc[4][8] = {};
        __syncthreads();
        bool wact = (wave * 64) < msize;
        const unsigned short* hrow[4];
        #pragma unroll
        for (int m = 0; m < 4; ++m) {
            int rowl = wave * 64 + m * 16 + lcol;
            hrow[m] = h + (size_t)(slotbase + m0 + rowl) * II;
        }
        for (int k0 = 0; k0 < II; k0 += 64) {
            #pragma unroll
            for (int r = 0; r < 8; ++r) {
                int kk = r * 8 + (tid >> 5);
                int nn = (tid & 31) * 4;
                const float4 w4 = *reinterpret_cast<const float4*>(&W[(size_t)(k0 + kk) * H + n0 + nn]);
                lW[nn + 0][kk] = f2bf(w4.x); lW[nn + 1][kk] = f2bf(w4.y);
                lW[nn + 2][kk] = f2bf(w4.z); lW[nn + 3][kk] = f2bf(w4.w);
            }
            __syncthreads();
            if (wact) {
                #pragma unroll
                for (int s = 0; s < 2; ++s) {
                    short8 a[4];
                    #pragma unroll
                    for (int m = 0; m < 4; ++m)
                        a[m] = *reinterpret_cast<const short8*>(&hrow[m][k0 + s * 32 + lkg * 8]);
                    #pragma unroll
                    for (int n = 0; n < 8; ++n) {
                        const short8 b = *reinterpret_cast<const short8*>(&lW[n * 16 + lcol][s * 32 + lkg * 8]);
                        #pragma unroll
                        for (int m = 0; m < 4; ++m)
                            acc[m][n] = __builtin_amdgcn_mfma_f32_16x16x32_bf16(a[m], b, acc[m][n], 0, 0, 0);
                    }
                }
            }
            __syncthreads();
        }
        if (wact) {
            #pragma unroll
            for (int m = 0; m < 4; ++m)
                #pragma unroll
                for (int n = 0; n < 8; ++n)
                    #pragma unroll
                    for (int r = 0; r < 4; ++r) {
                        int rowl = wave * 64 + m * 16 + lkg * 4 + r;
                        if (rowl < msize) {
                            int tok = tokL[rowl];
                            float wv = wtL[rowl];
                            unsafeAtomicAdd(&out[(size_t)tok * H + n0 + n * 16 + lcol],
                                            acc[m][n][r] * wv);
                        }
                    }
        }
        __syncthreads();
    }
}

extern "C" void kernel_launch(void* const* d_in, const int* in_sizes, int n_in,
                              void* d_out, int out_size, void* d_ws, size_t ws_size,
                              hipStream_t stream) {
    const float* x       = (const float*)d_in[0];
    const float* gate_w  = (const float*)d_in[1];
    const float* e_bias  = (const float*)d_in[2];
    const float* w_gate  = (const float*)d_in[3];
    const float* w_up    = (const float*)d_in[4];
    const float* w_down  = (const float*)d_in[5];
    const float* sw_gate = (const float*)d_in[6];
    const float* sw_up   = (const float*)d_in[7];
    const float* sw_down = (const float*)d_in[8];
    float* out = (float*)d_out;

    char* ws = (char*)d_ws;
    unsigned short* xbf = (unsigned short*)ws;                       // 4 MB
    int*   list = (int*)(ws + 4194304);                              // 132 KB
    float* wts  = (float*)(ws + 4194304 + 135168);                   // 132 KB
    int*   cnt  = (int*)(ws + 4194304 + 2 * 135168);                 // 256 B
    unsigned short* h = (unsigned short*)(ws + 4194304 + 2 * 135168 + 256); // ~37.5 MB

    hipMemsetAsync(d_out, 0, (size_t)T * H * sizeof(float), stream);
    prep_kernel<<<dim3(2048), dim3(256), 0, stream>>>(x, xbf, list, wts, cnt);
    router_kernel<<<dim3(T), dim3(256), 0, stream>>>(x, gate_w, e_bias, list, wts, cnt);
    passA_kernel<<<dim3(36, 22), dim3(256), 0, stream>>>(xbf, w_gate, w_up, sw_gate, sw_up, list, cnt, h);
    passB_kernel<<<dim3(36, 16), dim3(256), 0, stream>>>(h, w_down, sw_down, list, wts, cnt, out);
}

// Round 3
// 688.815 us; speedup vs baseline: 4.5421x; 1.1994x over previous
//
#include <hip/hip_runtime.h>
#include <cstdint>

#define T 1024
#define H 2048
#define II 1408
#define E 32
#define TOPK 6
#define NGRP 4
#define GSZ 8
#define CAP 1024
#define CAPH 384

typedef __attribute__((ext_vector_type(8))) short short8;
typedef __attribute__((ext_vector_type(4))) float f32x4;
typedef __attribute__((ext_vector_type(4))) unsigned short us4;

static __device__ __forceinline__ unsigned short f2bf(float f) {
    unsigned int u = __builtin_bit_cast(unsigned int, f);
    u += 0x7FFFu + ((u >> 16) & 1u);
    return (unsigned short)(u >> 16);
}

__global__ void prep_kernel(const float* __restrict__ x, unsigned short* __restrict__ xbf,
                            int* __restrict__ list, float* __restrict__ wts,
                            int* __restrict__ cnt) {
    int gid = blockIdx.x * blockDim.x + threadIdx.x;
    const int n4 = T * H / 4;
    if (gid < n4) {
        const float4 v = reinterpret_cast<const float4*>(x)[gid];
        us4 o;
        o.x = f2bf(v.x); o.y = f2bf(v.y); o.z = f2bf(v.z); o.w = f2bf(v.w);
        reinterpret_cast<us4*>(xbf)[gid] = o;
    }
    if (gid < T) { list[E * CAP + gid] = gid; wts[E * CAP + gid] = 1.0f; }
    if (gid < E + 1) cnt[gid] = (gid == E) ? T : 0;
}

__global__ __launch_bounds__(256) void router_kernel(
        const float* __restrict__ x, const float* __restrict__ gw,
        const float* __restrict__ bias, int* __restrict__ list,
        float* __restrict__ wts, int* __restrict__ cnt) {
    int t = blockIdx.x;
    int tid = threadIdx.x;
    int e = tid >> 3, p = tid & 7;
    const float4* xr = reinterpret_cast<const float4*>(x + (size_t)t * H);
    const float4* gr = reinterpret_cast<const float4*>(gw + (size_t)e * H);
    float part = 0.f;
    for (int q = 0; q < 64; ++q) {
        int idx = p * 64 + q;
        float4 a = xr[idx], b = gr[idx];
        part += a.x * b.x + a.y * b.y + a.z * b.z + a.w * b.w;
    }
    __shared__ float red[256];
    __shared__ float sc[E], sfc[E];
    red[tid] = part;
    __syncthreads();
    if (tid < E) {
        float s = 0.f;
        for (int j = 0; j < 8; ++j) s += red[tid * 8 + j];
        float sig = 1.f / (1.f + expf(-s));
        sc[tid] = sig;
        sfc[tid] = sig + bias[tid];
    }
    __syncthreads();
    if (tid == 0) {
        float gs[NGRP];
        for (int g = 0; g < NGRP; ++g) {
            float m1 = -INFINITY, m2 = -INFINITY;
            for (int j = 0; j < GSZ; ++j) {
                float v = sfc[g * GSZ + j];
                if (v > m1) { m2 = m1; m1 = v; }
                else if (v > m2) m2 = v;
            }
            gs[g] = m1 + m2;
        }
        int g1 = 0;
        for (int g = 1; g < NGRP; ++g) if (gs[g] > gs[g1]) g1 = g;
        int g2 = -1;
        for (int g = 0; g < NGRP; ++g) {
            if (g == g1) continue;
            if (g2 < 0 || gs[g] > gs[g2]) g2 = g;
        }
        int sel[TOPK];
        unsigned int usedmask = 0;
        float wsum = 0.f;
        for (int k = 0; k < TOPK; ++k) {
            float best = -INFINITY; int bi = -1;
            for (int ee = 0; ee < E; ++ee) {
                int g = ee >> 3;
                if (g != g1 && g != g2) continue;
                if (usedmask & (1u << ee)) continue;
                if (sfc[ee] > best) { best = sfc[ee]; bi = ee; }
            }
            usedmask |= (1u << bi);
            sel[k] = bi;
            wsum += sc[bi];
        }
        float fac = 2.5f / (wsum + 1e-20f);
        for (int k = 0; k < TOPK; ++k) {
            int ee = sel[k];
            int pos = atomicAdd(&cnt[ee], 1);
            list[ee * CAP + pos] = t;
            wts[ee * CAP + pos] = sc[ee] * fac;
        }
    }
}

// Pass A: h = silu(x@Wg)*(x@Wu). Double-buffered LDS, reg-prefetched global
// loads (latency hides under MFMA), XOR-swizzled LDS transpose layout.
__global__ __launch_bounds__(256) void passA_kernel(
        const unsigned short* __restrict__ xbf,
        const float* __restrict__ wgate, const float* __restrict__ wup,
        const float* __restrict__ swgate, const float* __restrict__ swup,
        const int* __restrict__ list, const int* __restrict__ cnt,
        unsigned short* __restrict__ h) {
    int bx = blockIdx.x;
    int ve, start, end;
    if (bx < E) { ve = bx; start = 0; end = cnt[ve]; }
    else        { ve = E; start = (bx - E) * 256; end = start + 256; }
    if (start >= end) return;
    const float* G = (ve < E) ? wgate + (size_t)ve * H * II : swgate;
    const float* U = (ve < E) ? wup   + (size_t)ve * H * II : swup;
    int i0 = blockIdx.y * 64;
    int tid = threadIdx.x, wave = tid >> 6, lane = tid & 63;
    int lcol = lane & 15, lkg = lane >> 4;
    __shared__ unsigned short lG[2][64 * 64];  // byte addr = i*128 + k*2, ^swz(i)
    __shared__ unsigned short lU[2][64 * 64];
    __shared__ int tokL[256];
    int slotbase = (ve < E) ? ve * CAPH : E * CAPH;

    const int wk = tid >> 4;                       // k row within 16-group
    const int wc = tid & 15;                       // i group (i = wc*4 + c)
    const unsigned int swzw = ((unsigned)(wc & 7)) << 4;
    const unsigned int wbase = (unsigned)wc * 512 + (unsigned)wk * 2;
    const float* Gp = G + (size_t)wk * II + i0 + wc * 4;
    const float* Up = U + (size_t)wk * II + i0 + wc * 4;

    for (int m0 = start; m0 < end; m0 += 256) {
        int msize = min(256, end - m0);
        tokL[tid] = (tid < msize) ? list[ve * CAP + m0 + tid] : 0;
        f32x4 accg[4][4] = {};
        f32x4 accu[4][4] = {};
        float4 pg[4], pu[4];
        #pragma unroll
        for (int r = 0; r < 4; ++r) {
            pg[r] = *reinterpret_cast<const float4*>(Gp + (size_t)(r * 16) * II);
            pu[r] = *reinterpret_cast<const float4*>(Up + (size_t)(r * 16) * II);
        }
        {
            char* dg = (char*)&lG[0][0];
            char* du = (char*)&lU[0][0];
            #pragma unroll
            for (int r = 0; r < 4; ++r) {
                unsigned int a = wbase + (unsigned)(r * 32);
                *(unsigned short*)(dg + ((a +   0) ^ swzw)) = f2bf(pg[r].x);
                *(unsigned short*)(dg + ((a + 128) ^ swzw)) = f2bf(pg[r].y);
                *(unsigned short*)(dg + ((a + 256) ^ swzw)) = f2bf(pg[r].z);
                *(unsigned short*)(dg + ((a + 384) ^ swzw)) = f2bf(pg[r].w);
                *(unsigned short*)(du + ((a +   0) ^ swzw)) = f2bf(pu[r].x);
                *(unsigned short*)(du + ((a + 128) ^ swzw)) = f2bf(pu[r].y);
                *(unsigned short*)(du + ((a + 256) ^ swzw)) = f2bf(pu[r].z);
                *(unsigned short*)(du + ((a + 384) ^ swzw)) = f2bf(pu[r].w);
            }
        }
        __syncthreads();
        const unsigned short* xrow[4];
        #pragma unroll
        for (int m = 0; m < 4; ++m)
            xrow[m] = xbf + (size_t)tokL[wave * 64 + m * 16 + lcol] * H;
        bool wact = (wave * 64) < msize;

        for (int ks = 0; ks < 32; ++ks) {
            int cur = ks & 1;
            if (ks + 1 < 32) {
                const float* Gn = Gp + (size_t)(ks + 1) * 64 * II;
                const float* Un = Up + (size_t)(ks + 1) * 64 * II;
                #pragma unroll
                for (int r = 0; r < 4; ++r) {
                    pg[r] = *reinterpret_cast<const float4*>(Gn + (size_t)(r * 16) * II);
                    pu[r] = *reinterpret_cast<const float4*>(Un + (size_t)(r * 16) * II);
                }
            }
            if (wact) {
                const char* bg0 = (const char*)&lG[cur][0];
                const char* bu0 = (const char*)&lU[cur][0];
                int k0 = ks * 64;
                #pragma unroll
                for (int s = 0; s < 2; ++s) {
                    short8 a[4];
                    #pragma unroll
                    for (int m = 0; m < 4; ++m)
                        a[m] = *reinterpret_cast<const short8*>(&xrow[m][k0 + s * 32 + lkg * 8]);
                    #pragma unroll
                    for (int n = 0; n < 4; ++n) {
                        unsigned int ra = (unsigned)(n * 16 + lcol) * 128 + (unsigned)(s * 64 + lkg * 16);
                        ra ^= ((unsigned)((n * 4 + (lcol >> 2)) & 7)) << 4;
                        const short8 bg = *reinterpret_cast<const short8*>(bg0 + ra);
                        const short8 bu = *reinterpret_cast<const short8*>(bu0 + ra);
                        #pragma unroll
                        for (int m = 0; m < 4; ++m) {
                            accg[m][n] = __builtin_amdgcn_mfma_f32_16x16x32_bf16(a[m], bg, accg[m][n], 0, 0, 0);
                            accu[m][n] = __builtin_amdgcn_mfma_f32_16x16x32_bf16(a[m], bu, accu[m][n], 0, 0, 0);
                        }
                    }
                }
            }
            __syncthreads();
            if (ks + 1 < 32) {
                char* dg = (char*)&lG[cur ^ 1][0];
                char* du = (char*)&lU[cur ^ 1][0];
                #pragma unroll
                for (int r = 0; r < 4; ++r) {
                    unsigned int a = wbase + (unsigned)(r * 32);
                    *(unsigned short*)(dg + ((a +   0) ^ swzw)) = f2bf(pg[r].x);
                    *(unsigned short*)(dg + ((a + 128) ^ swzw)) = f2bf(pg[r].y);
                    *(unsigned short*)(dg + ((a + 256) ^ swzw)) = f2bf(pg[r].z);
                    *(unsigned short*)(dg + ((a + 384) ^ swzw)) = f2bf(pg[r].w);
                    *(unsigned short*)(du + ((a +   0) ^ swzw)) = f2bf(pu[r].x);
                    *(unsigned short*)(du + ((a + 128) ^ swzw)) = f2bf(pu[r].y);
                    *(unsigned short*)(du + ((a + 256) ^ swzw)) = f2bf(pu[r].z);
                    *(unsigned short*)(du + ((a + 384) ^ swzw)) = f2bf(pu[r].w);
                }
            }
            __syncthreads();
        }
        if (wact) {
            #pragma unroll
            for (int m = 0; m < 4; ++m)
                #pragma unroll
                for (int n = 0; n < 4; ++n)
                    #pragma unroll
                    for (int r = 0; r < 4; ++r) {
                        int rowl = wave * 64 + m * 16 + lkg * 4 + r;
                        int pos = m0 + rowl;
                        bool ok = (rowl < msize) && !(ve < E && pos >= CAPH);
                        float gv = accg[m][n][r], uv = accu[m][n][r];
                        float hv = gv / (1.f + expf(-gv)) * uv;
                        if (ok)
                            h[(size_t)(slotbase + pos) * II + i0 + n * 16 + lcol] = f2bf(hv);
                    }
        }
        __syncthreads();
    }
}

// Pass B: out[tok] += wt * (h @ Wdown). Same pipeline + swizzle.
__global__ __launch_bounds__(256) void passB_kernel(
        const unsigned short* __restrict__ h,
        const float* __restrict__ wdown, const float* __restrict__ swdown,
        const int* __restrict__ list, const float* __restrict__ wts,
        const int* __restrict__ cnt, float* __restrict__ out) {
    int bx = blockIdx.x;
    int ve, start, end;
    if (bx < E) { ve = bx; start = 0; end = cnt[ve]; }
    else        { ve = E; start = (bx - E) * 256; end = start + 256; }
    if (start >= end) return;
    const float* W = (ve < E) ? wdown + (size_t)ve * II * H : swdown;
    int n0 = blockIdx.y * 128;
    int tid = threadIdx.x, wave = tid >> 6, lane = tid & 63;
    int lcol = lane & 15, lkg = lane >> 4;
    __shared__ unsigned short lW[2][128 * 64];   // byte = i*128 + k*2, ^swz(i)
    __shared__ int tokL[256];
    __shared__ float wtL[256];
    int slotbase = (ve < E) ? ve * CAPH : E * CAPH;

    const int wk = tid >> 5;                     // 0..7
    const int wc = tid & 31;                     // i group (i = wc*4 + c)
    const unsigned int swzw = ((unsigned)(wc & 7)) << 4;
    const unsigned int wbase = (unsigned)wc * 512 + (unsigned)wk * 2;
    const float* Wp = W + (size_t)wk * H + n0 + wc * 4;
    const int NS = II / 64;  // 22

    for (int m0 = start; m0 < end; m0 += 256) {
        int msize = min(256, end - m0);
        tokL[tid] = (tid < msize) ? list[ve * CAP + m0 + tid] : 0;
        wtL[tid]  = (tid < msize) ? wts[ve * CAP + m0 + tid] : 0.f;
        f32x4 acc[4][8] = {};
        float4 pw[8];
        #pragma unroll
        for (int r = 0; r < 8; ++r)
            pw[r] = *reinterpret_cast<const float4*>(Wp + (size_t)(r * 8) * H);
        {
            char* dw = (char*)&lW[0][0];
            #pragma unroll
            for (int r = 0; r < 8; ++r) {
                unsigned int a = wbase + (unsigned)(r * 16);
                *(unsigned short*)(dw + ((a +   0) ^ swzw)) = f2bf(pw[r].x);
                *(unsigned short*)(dw + ((a + 128) ^ swzw)) = f2bf(pw[r].y);
                *(unsigned short*)(dw + ((a + 256) ^ swzw)) = f2bf(pw[r].z);
                *(unsigned short*)(dw + ((a + 384) ^ swzw)) = f2bf(pw[r].w);
            }
        }
        __syncthreads();
        const unsigned short* hrow[4];
        #pragma unroll
        for (int m = 0; m < 4; ++m)
            hrow[m] = h + (size_t)(slotbase + m0 + wave * 64 + m * 16 + lcol) * II;
        bool wact = (wave * 64) < msize;

        for (int ks = 0; ks < NS; ++ks) {
            int cur = ks & 1;
            if (ks + 1 < NS) {
                const float* Wn = Wp + (size_t)(ks + 1) * 64 * H;
                #pragma unroll
                for (int r = 0; r < 8; ++r)
                    pw[r] = *reinterpret_cast<const float4*>(Wn + (size_t)(r * 8) * H);
            }
            if (wact) {
                const char* bw0 = (const char*)&lW[cur][0];
                int k0 = ks * 64;
                #pragma unroll
                for (int s = 0; s < 2; ++s) {
                    short8 a[4];
                    #pragma unroll
                    for (int m = 0; m < 4; ++m)
                        a[m] = *reinterpret_cast<const short8*>(&hrow[m][k0 + s * 32 + lkg * 8]);
                    #pragma unroll
                    for (int n = 0; n < 8; ++n) {
                        unsigned int ra = (unsigned)(n * 16 + lcol) * 128 + (unsigned)(s * 64 + lkg * 16);
                        ra ^= ((unsigned)((n * 4 + (lcol >> 2)) & 7)) << 4;
                        const short8 b = *reinterpret_cast<const short8*>(bw0 + ra);
                        #pragma unroll
                        for (int m = 0; m < 4; ++m)
                            acc[m][n] = __builtin_amdgcn_mfma_f32_16x16x32_bf16(a[m], b, acc[m][n], 0, 0, 0);
                    }
                }
            }
            __syncthreads();
            if (ks + 1 < NS) {
                char* dw = (char*)&lW[cur ^ 1][0];
                #pragma unroll
                for (int r = 0; r < 8; ++r) {
                    unsigned int a = wbase + (unsigned)(r * 16);
                    *(unsigned short*)(dw + ((a +   0) ^ swzw)) = f2bf(pw[r].x);
                    *(unsigned short*)(dw + ((a + 128) ^ swzw)) = f2bf(pw[r].y);
                    *(unsigned short*)(dw + ((a + 256) ^ swzw)) = f2bf(pw[r].z);
                    *(unsigned short*)(dw + ((a + 384) ^ swzw)) = f2bf(pw[r].w);
                }
            }
            __syncthreads();
        }
        if (wact) {
            #pragma unroll
            for (int m = 0; m < 4; ++m)
                #pragma unroll
                for (int n = 0; n < 8; ++n)
                    #pragma unroll
                    for (int r = 0; r < 4; ++r) {
                        int rowl = wave * 64 + m * 16 + lkg * 4 + r;
                        if (rowl < msize) {
                            int tok = tokL[rowl];
                            float wv = wtL[rowl];
                            unsafeAtomicAdd(&out[(size_t)tok * H + n0 + n * 16 + lcol],
                                            acc[m][n][r] * wv);
                        }
                    }
        }
        __syncthreads();
    }
}

extern "C" void kernel_launch(void* const* d_in, const int* in_sizes, int n_in,
                              void* d_out, int out_size, void* d_ws, size_t ws_size,
                              hipStream_t stream) {
    const float* x       = (const float*)d_in[0];
    const float* gate_w  = (const float*)d_in[1];
    const float* e_bias  = (const float*)d_in[2];
    const float* w_gate  = (const float*)d_in[3];
    const float* w_up    = (const float*)d_in[4];
    const float* w_down  = (const float*)d_in[5];
    const float* sw_gate = (const float*)d_in[6];
    const float* sw_up   = (const float*)d_in[7];
    const float* sw_down = (const float*)d_in[8];
    float* out = (float*)d_out;

    char* ws = (char*)d_ws;
    unsigned short* xbf = (unsigned short*)ws;                       // 4 MB
    int*   list = (int*)(ws + 4194304);                              // 132 KB
    float* wts  = (float*)(ws + 4194304 + 135168);                   // 132 KB
    int*   cnt  = (int*)(ws + 4194304 + 2 * 135168);                 // 256 B
    unsigned short* h = (unsigned short*)(ws + 4194304 + 2 * 135168 + 256); // ~37.5 MB

    hipMemsetAsync(d_out, 0, (size_t)T * H * sizeof(float), stream);
    prep_kernel<<<dim3(2048), dim3(256), 0, stream>>>(x, xbf, list, wts, cnt);
    router_kernel<<<dim3(T), dim3(256), 0, stream>>>(x, gate_w, e_bias, list, wts, cnt);
    passA_kernel<<<dim3(36, 22), dim3(256), 0, stream>>>(xbf, w_gate, w_up, sw_gate, sw_up, list, cnt, h);
    passB_kernel<<<dim3(36, 16), dim3(256), 0, stream>>>(h, w_down, sw_down, list, wts, cnt, out);
}

// Round 4
// 636.193 us; speedup vs baseline: 4.9178x; 1.0827x over previous
//
#include <hip/hip_runtime.h>
#include <cstdint>

#define T 1024
#define H 2048
#define II 1408
#define E 32
#define TOPK 6
#define NGRP 4
#define GSZ 8
#define CAP 1024
#define CAPH 384

typedef __attribute__((ext_vector_type(8))) short short8;
typedef __attribute__((ext_vector_type(4))) float f32x4;
typedef __attribute__((ext_vector_type(2))) unsigned int u32x2;
typedef __attribute__((ext_vector_type(4))) unsigned short us4;

static __device__ __forceinline__ unsigned short f2bf(float f) {
    unsigned int u = __builtin_bit_cast(unsigned int, f);
    u += 0x7FFFu + ((u >> 16) & 1u);
    return (unsigned short)(u >> 16);
}

__global__ void prep_kernel(const float* __restrict__ x, unsigned short* __restrict__ xbf,
                            int* __restrict__ list, float* __restrict__ wts,
                            int* __restrict__ cnt) {
    int gid = blockIdx.x * blockDim.x + threadIdx.x;
    const int n4 = T * H / 4;
    if (gid < n4) {
        const float4 v = reinterpret_cast<const float4*>(x)[gid];
        us4 o;
        o.x = f2bf(v.x); o.y = f2bf(v.y); o.z = f2bf(v.z); o.w = f2bf(v.w);
        reinterpret_cast<us4*>(xbf)[gid] = o;
    }
    if (gid < T) { list[E * CAP + gid] = gid; wts[E * CAP + gid] = 1.0f; }
    if (gid < E + 1) cnt[gid] = (gid == E) ? T : 0;
}

__global__ __launch_bounds__(256) void router_kernel(
        const float* __restrict__ x, const float* __restrict__ gw,
        const float* __restrict__ bias, int* __restrict__ list,
        float* __restrict__ wts, int* __restrict__ cnt) {
    int t = blockIdx.x;
    int tid = threadIdx.x;
    int e = tid >> 3, p = tid & 7;
    const float4* xr = reinterpret_cast<const float4*>(x + (size_t)t * H);
    const float4* gr = reinterpret_cast<const float4*>(gw + (size_t)e * H);
    float part = 0.f;
    for (int q = 0; q < 64; ++q) {
        int idx = p * 64 + q;
        float4 a = xr[idx], b = gr[idx];
        part += a.x * b.x + a.y * b.y + a.z * b.z + a.w * b.w;
    }
    __shared__ float red[256];
    __shared__ float sc[E], sfc[E];
    red[tid] = part;
    __syncthreads();
    if (tid < E) {
        float s = 0.f;
        for (int j = 0; j < 8; ++j) s += red[tid * 8 + j];
        float sig = 1.f / (1.f + expf(-s));
        sc[tid] = sig;
        sfc[tid] = sig + bias[tid];
    }
    __syncthreads();
    if (tid == 0) {
        float gs[NGRP];
        for (int g = 0; g < NGRP; ++g) {
            float m1 = -INFINITY, m2 = -INFINITY;
            for (int j = 0; j < GSZ; ++j) {
                float v = sfc[g * GSZ + j];
                if (v > m1) { m2 = m1; m1 = v; }
                else if (v > m2) m2 = v;
            }
            gs[g] = m1 + m2;
        }
        int g1 = 0;
        for (int g = 1; g < NGRP; ++g) if (gs[g] > gs[g1]) g1 = g;
        int g2 = -1;
        for (int g = 0; g < NGRP; ++g) {
            if (g == g1) continue;
            if (g2 < 0 || gs[g] > gs[g2]) g2 = g;
        }
        int sel[TOPK];
        unsigned int usedmask = 0;
        float wsum = 0.f;
        for (int k = 0; k < TOPK; ++k) {
            float best = -INFINITY; int bi = -1;
            for (int ee = 0; ee < E; ++ee) {
                int g = ee >> 3;
                if (g != g1 && g != g2) continue;
                if (usedmask & (1u << ee)) continue;
                if (sfc[ee] > best) { best = sfc[ee]; bi = ee; }
            }
            usedmask |= (1u << bi);
            sel[k] = bi;
            wsum += sc[bi];
        }
        float fac = 2.5f / (wsum + 1e-20f);
        for (int k = 0; k < TOPK; ++k) {
            int ee = sel[k];
            int pos = atomicAdd(&cnt[ee], 1);
            list[ee * CAP + pos] = t;
            wts[ee * CAP + pos] = sc[ee] * fac;
        }
    }
}

// Pass A: h = silu(x@Wg)*(x@Wu). 256x32 tile, 4 blocks/CU, 1 barrier/K-step,
// vectorized b64 LDS staging with bank-uniform XOR swizzle.
__global__ __launch_bounds__(256, 4) void passA_kernel(
        const unsigned short* __restrict__ xbf,
        const float* __restrict__ wgate, const float* __restrict__ wup,
        const float* __restrict__ swgate, const float* __restrict__ swup,
        const int* __restrict__ list, const int* __restrict__ cnt,
        unsigned short* __restrict__ h) {
    int bx = blockIdx.x;
    int ve, start, end;
    if (bx < E) { ve = bx; start = 0; end = cnt[ve]; }
    else        { ve = E; start = (bx - E) * 256; end = start + 256; }
    if (start >= end) return;
    const int i0 = blockIdx.y * 32;
    const int tid = threadIdx.x, wave = tid >> 6, lane = tid & 63;
    const int lcol = lane & 15, lkg = lane >> 4;
    // staging roles: 128 threads per matrix; wcq = i-quad (contiguous), wkq = k-quad
    const int mat = tid >> 7;
    const int wcq = tid & 7;
    const int wkq = (tid >> 3) & 15;
    const float* G = (ve < E) ? wgate + (size_t)ve * H * II : swgate;
    const float* U = (ve < E) ? wup   + (size_t)ve * H * II : swup;
    const float* Wsrc = (mat ? U : G) + (size_t)(wkq * 4) * II + i0 + wcq * 4;
    __shared__ unsigned short lB[2][2][32 * 64];   // [buf][mat][row i][k]
    __shared__ int tokL[256];
    const int slotbase = (ve < E) ? ve * CAPH : E * CAPH;

#define STAGE_A(BUF) { \
        char* dst = (char*)&lB[BUF][mat][0]; \
        _Pragma("unroll") \
        for (int c = 0; c < 4; ++c) { \
            int ii = wcq * 4 + c; \
            unsigned int ad = ((unsigned)ii * 128 + (unsigned)wkq * 8) ^ (((unsigned)(ii & 7)) << 4); \
            u32x2 pk; \
            pk[0] = (unsigned)f2bf(pf[0][c]) | ((unsigned)f2bf(pf[1][c]) << 16); \
            pk[1] = (unsigned)f2bf(pf[2][c]) | ((unsigned)f2bf(pf[3][c]) << 16); \
            *reinterpret_cast<u32x2*>(dst + ad) = pk; \
        } }

    for (int m0 = start; m0 < end; m0 += 256) {
        int msize = min(256, end - m0);
        tokL[tid] = (tid < msize) ? list[ve * CAP + m0 + tid] : 0;
        f32x4 accg[4][2] = {};
        f32x4 accu[4][2] = {};
        f32x4 pf[4];
        #pragma unroll
        for (int q = 0; q < 4; ++q)
            pf[q] = *reinterpret_cast<const f32x4*>(Wsrc + (size_t)q * II);
        STAGE_A(0)
        __syncthreads();
        const unsigned short* xrow[4];
        #pragma unroll
        for (int m = 0; m < 4; ++m)
            xrow[m] = xbf + (size_t)tokL[wave * 64 + m * 16 + lcol] * H;
        bool wact = (wave * 64) < msize;

        for (int ks = 0; ks < 32; ++ks) {
            const int cur = ks & 1;
            if (ks + 1 < 32) {
                const float* src = Wsrc + (size_t)((ks + 1) * 64) * II;
                #pragma unroll
                for (int q = 0; q < 4; ++q)
                    pf[q] = *reinterpret_cast<const f32x4*>(src + (size_t)q * II);
            }
            if (wact) {
                const char* b0 = (const char*)&lB[cur][0][0];
                const char* b1 = (const char*)&lB[cur][1][0];
                const int k0 = ks * 64;
                #pragma unroll
                for (int s = 0; s < 2; ++s) {
                    short8 a[4];
                    #pragma unroll
                    for (int m = 0; m < 4; ++m)
                        a[m] = *reinterpret_cast<const short8*>(&xrow[m][k0 + s * 32 + lkg * 8]);
                    #pragma unroll
                    for (int n = 0; n < 2; ++n) {
                        unsigned int ra = ((unsigned)(n * 16 + lcol) * 128 + (unsigned)(s * 64 + lkg * 16))
                                        ^ (((unsigned)(lcol & 7)) << 4);
                        const short8 bg = *reinterpret_cast<const short8*>(b0 + ra);
                        const short8 bu = *reinterpret_cast<const short8*>(b1 + ra);
                        #pragma unroll
                        for (int m = 0; m < 4; ++m) {
                            accg[m][n] = __builtin_amdgcn_mfma_f32_16x16x32_bf16(a[m], bg, accg[m][n], 0, 0, 0);
                            accu[m][n] = __builtin_amdgcn_mfma_f32_16x16x32_bf16(a[m], bu, accu[m][n], 0, 0, 0);
                        }
                    }
                }
            }
            if (ks + 1 < 32) STAGE_A(cur ^ 1)
            __syncthreads();
        }
        if (wact) {
            #pragma unroll
            for (int m = 0; m < 4; ++m)
                #pragma unroll
                for (int n = 0; n < 2; ++n)
                    #pragma unroll
                    for (int r = 0; r < 4; ++r) {
                        int rowl = wave * 64 + m * 16 + lkg * 4 + r;
                        int pos = m0 + rowl;
                        bool ok = (rowl < msize) && !(ve < E && pos >= CAPH);
                        float gv = accg[m][n][r], uv = accu[m][n][r];
                        float hv = gv / (1.f + expf(-gv)) * uv;
                        if (ok)
                            h[(size_t)(slotbase + pos) * II + i0 + n * 16 + lcol] = f2bf(hv);
                    }
        }
        __syncthreads();
    }
#undef STAGE_A
}

// Pass B: out[tok] += wt * (h @ Wdown). 256x64 tile, same structure.
__global__ __launch_bounds__(256, 4) void passB_kernel(
        const unsigned short* __restrict__ h,
        const float* __restrict__ wdown, const float* __restrict__ swdown,
        const int* __restrict__ list, const float* __restrict__ wts,
        const int* __restrict__ cnt, float* __restrict__ out) {
    int bx = blockIdx.x;
    int ve, start, end;
    if (bx < E) { ve = bx; start = 0; end = cnt[ve]; }
    else        { ve = E; start = (bx - E) * 256; end = start + 256; }
    if (start >= end) return;
    const float* W = (ve < E) ? wdown + (size_t)ve * II * H : swdown;
    const int n0 = blockIdx.y * 64;
    const int tid = threadIdx.x, wave = tid >> 6, lane = tid & 63;
    const int lcol = lane & 15, lkg = lane >> 4;
    const int wnq = tid & 15;          // n-quad (contiguous dim)
    const int wkq = tid >> 4;          // k-quad
    const float* Wsrc = W + (size_t)(wkq * 4) * H + n0 + wnq * 4;
    __shared__ unsigned short lW[2][64 * 64];   // [buf][row n][k]
    __shared__ int tokL[256];
    __shared__ float wtL[256];
    const int slotbase = (ve < E) ? ve * CAPH : E * CAPH;
    const int NS = II / 64;  // 22

#define STAGE_B(BUF) { \
        char* dst = (char*)&lW[BUF][0]; \
        _Pragma("unroll") \
        for (int c = 0; c < 4; ++c) { \
            int nn = wnq * 4 + c; \
            unsigned int ad = ((unsigned)nn * 128 + (unsigned)wkq * 8) ^ (((unsigned)(nn & 7)) << 4); \
            u32x2 pk; \
            pk[0] = (unsigned)f2bf(pf[0][c]) | ((unsigned)f2bf(pf[1][c]) << 16); \
            pk[1] = (unsigned)f2bf(pf[2][c]) | ((unsigned)f2bf(pf[3][c]) << 16); \
            *reinterpret_cast<u32x2*>(dst + ad) = pk; \
        } }

    for (int m0 = start; m0 < end; m0 += 256) {
        int msize = min(256, end - m0);
        tokL[tid] = (tid < msize) ? list[ve * CAP + m0 + tid] : 0;
        wtL[tid]  = (tid < msize) ? wts[ve * CAP + m0 + tid] : 0.f;
        f32x4 acc[4][4] = {};
        f32x4 pf[4];
        #pragma unroll
        for (int q = 0; q < 4; ++q)
            pf[q] = *reinterpret_cast<const f32x4*>(Wsrc + (size_t)q * H);
        STAGE_B(0)
        __syncthreads();
        const unsigned short* hrow[4];
        #pragma unroll
        for (int m = 0; m < 4; ++m)
            hrow[m] = h + (size_t)(slotbase + m0 + wave * 64 + m * 16 + lcol) * II;
        bool wact = (wave * 64) < msize;

        for (int ks = 0; ks < NS; ++ks) {
            const int cur = ks & 1;
            if (ks + 1 < NS) {
                const float* src = Wsrc + (size_t)((ks + 1) * 64) * H;
                #pragma unroll
                for (int q = 0; q < 4; ++q)
                    pf[q] = *reinterpret_cast<const f32x4*>(src + (size_t)q * H);
            }
            if (wact) {
                const char* bw0 = (const char*)&lW[cur][0];
                const int k0 = ks * 64;
                #pragma unroll
                for (int s = 0; s < 2; ++s) {
                    short8 a[4];
                    #pragma unroll
                    for (int m = 0; m < 4; ++m)
                        a[m] = *reinterpret_cast<const short8*>(&hrow[m][k0 + s * 32 + lkg * 8]);
                    #pragma unroll
                    for (int n = 0; n < 4; ++n) {
                        unsigned int ra = ((unsigned)(n * 16 + lcol) * 128 + (unsigned)(s * 64 + lkg * 16))
                                        ^ (((unsigned)(lcol & 7)) << 4);
                        const short8 b = *reinterpret_cast<const short8*>(bw0 + ra);
                        #pragma unroll
                        for (int m = 0; m < 4; ++m)
                            acc[m][n] = __builtin_amdgcn_mfma_f32_16x16x32_bf16(a[m], b, acc[m][n], 0, 0, 0);
                    }
                }
            }
            if (ks + 1 < NS) STAGE_B(cur ^ 1)
            __syncthreads();
        }
        if (wact) {
            #pragma unroll
            for (int m = 0; m < 4; ++m)
                #pragma unroll
                for (int n = 0; n < 4; ++n)
                    #pragma unroll
                    for (int r = 0; r < 4; ++r) {
                        int rowl = wave * 64 + m * 16 + lkg * 4 + r;
                        if (rowl < msize) {
                            int tok = tokL[rowl];
                            float wv = wtL[rowl];
                            unsafeAtomicAdd(&out[(size_t)tok * H + n0 + n * 16 + lcol],
                                            acc[m][n][r] * wv);
                        }
                    }
        }
        __syncthreads();
    }
#undef STAGE_B
}

extern "C" void kernel_launch(void* const* d_in, const int* in_sizes, int n_in,
                              void* d_out, int out_size, void* d_ws, size_t ws_size,
                              hipStream_t stream) {
    const float* x       = (const float*)d_in[0];
    const float* gate_w  = (const float*)d_in[1];
    const float* e_bias  = (const float*)d_in[2];
    const float* w_gate  = (const float*)d_in[3];
    const float* w_up    = (const float*)d_in[4];
    const float* w_down  = (const float*)d_in[5];
    const float* sw_gate = (const float*)d_in[6];
    const float* sw_up   = (const float*)d_in[7];
    const float* sw_down = (const float*)d_in[8];
    float* out = (float*)d_out;

    char* ws = (char*)d_ws;
    unsigned short* xbf = (unsigned short*)ws;                       // 4 MB
    int*   list = (int*)(ws + 4194304);                              // 132 KB
    float* wts  = (float*)(ws + 4194304 + 135168);                   // 132 KB
    int*   cnt  = (int*)(ws + 4194304 + 2 * 135168);                 // 256 B
    unsigned short* h = (unsigned short*)(ws + 4194304 + 2 * 135168 + 256); // ~37.5 MB

    hipMemsetAsync(d_out, 0, (size_t)T * H * sizeof(float), stream);
    prep_kernel<<<dim3(2048), dim3(256), 0, stream>>>(x, xbf, list, wts, cnt);
    router_kernel<<<dim3(T), dim3(256), 0, stream>>>(x, gate_w, e_bias, list, wts, cnt);
    passA_kernel<<<dim3(36, 44), dim3(256), 0, stream>>>(xbf, w_gate, w_up, sw_gate, sw_up, list, cnt, h);
    passB_kernel<<<dim3(36, 32), dim3(256), 0, stream>>>(h, w_down, sw_down, list, wts, cnt, out);
}

// Round 5
// 513.044 us; speedup vs baseline: 6.0982x; 1.2400x over previous
//
#include <hip/hip_runtime.h>
#include <cstdint>

#define T 1024
#define H 2048
#define II 1408
#define E 32
#define TOPK 6
#define NGRP 4
#define GSZ 8
#define CAP 1024
#define CAPH 384

typedef __attribute__((ext_vector_type(8))) short short8;
typedef __attribute__((ext_vector_type(4))) float f32x4;
typedef __attribute__((ext_vector_type(2))) unsigned int u32x2;
typedef __attribute__((ext_vector_type(4))) unsigned short us4;

static __device__ __forceinline__ unsigned short f2bf(float f) {
    unsigned int u = __builtin_bit_cast(unsigned int, f);
    u += 0x7FFFu + ((u >> 16) & 1u);
    return (unsigned short)(u >> 16);
}

static __device__ __forceinline__ unsigned int cvtpk(float lo, float hi) {
    unsigned int r;
    asm("v_cvt_pk_bf16_f32 %0, %1, %2" : "=v"(r) : "v"(lo), "v"(hi));
    return r;
}

__global__ void prep_kernel(const float* __restrict__ x, unsigned short* __restrict__ xbf,
                            int* __restrict__ list, float* __restrict__ wts,
                            int* __restrict__ cnt) {
    int gid = blockIdx.x * blockDim.x + threadIdx.x;
    const int n4 = T * H / 4;
    if (gid < n4) {
        const float4 v = reinterpret_cast<const float4*>(x)[gid];
        us4 o;
        o.x = f2bf(v.x); o.y = f2bf(v.y); o.z = f2bf(v.z); o.w = f2bf(v.w);
        reinterpret_cast<us4*>(xbf)[gid] = o;
    }
    if (gid < T) { list[E * CAP + gid] = gid; wts[E * CAP + gid] = 1.0f; }
    if (gid < E + 1) cnt[gid] = (gid == E) ? T : 0;
}

__global__ __launch_bounds__(256) void router_kernel(
        const float* __restrict__ x, const float* __restrict__ gw,
        const float* __restrict__ bias, int* __restrict__ list,
        float* __restrict__ wts, int* __restrict__ cnt) {
    int t = blockIdx.x;
    int tid = threadIdx.x;
    int e = tid >> 3, p = tid & 7;
    const float4* xr = reinterpret_cast<const float4*>(x + (size_t)t * H);
    const float4* gr = reinterpret_cast<const float4*>(gw + (size_t)e * H);
    float part = 0.f;
    for (int q = 0; q < 64; ++q) {
        int idx = p * 64 + q;
        float4 a = xr[idx], b = gr[idx];
        part += a.x * b.x + a.y * b.y + a.z * b.z + a.w * b.w;
    }
    __shared__ float red[256];
    __shared__ float sc[E], sfc[E];
    red[tid] = part;
    __syncthreads();
    if (tid < E) {
        float s = 0.f;
        for (int j = 0; j < 8; ++j) s += red[tid * 8 + j];
        float sig = 1.f / (1.f + expf(-s));
        sc[tid] = sig;
        sfc[tid] = sig + bias[tid];
    }
    __syncthreads();
    if (tid == 0) {
        float gs[NGRP];
        for (int g = 0; g < NGRP; ++g) {
            float m1 = -INFINITY, m2 = -INFINITY;
            for (int j = 0; j < GSZ; ++j) {
                float v = sfc[g * GSZ + j];
                if (v > m1) { m2 = m1; m1 = v; }
                else if (v > m2) m2 = v;
            }
            gs[g] = m1 + m2;
        }
        int g1 = 0;
        for (int g = 1; g < NGRP; ++g) if (gs[g] > gs[g1]) g1 = g;
        int g2 = -1;
        for (int g = 0; g < NGRP; ++g) {
            if (g == g1) continue;
            if (g2 < 0 || gs[g] > gs[g2]) g2 = g;
        }
        int sel[TOPK];
        unsigned int usedmask = 0;
        float wsum = 0.f;
        for (int k = 0; k < TOPK; ++k) {
            float best = -INFINITY; int bi = -1;
            for (int ee = 0; ee < E; ++ee) {
                int g = ee >> 3;
                if (g != g1 && g != g2) continue;
                if (usedmask & (1u << ee)) continue;
                if (sfc[ee] > best) { best = sfc[ee]; bi = ee; }
            }
            usedmask |= (1u << bi);
            sel[k] = bi;
            wsum += sc[bi];
        }
        float fac = 2.5f / (wsum + 1e-20f);
        for (int k = 0; k < TOPK; ++k) {
            int ee = sel[k];
            int pos = atomicAdd(&cnt[ee], 1);
            list[ee * CAP + pos] = t;
            wts[ee * CAP + pos] = sc[ee] * fac;
        }
    }
}

// Pass A: h = silu(x@Wg)*(x@Wu). a-gathers issued FIRST, weight prefetch
// SECOND (sched_barrier-pinned) so compute waits vmcnt(4), not vmcnt(0).
__global__ __launch_bounds__(256, 3) void passA_kernel(
        const unsigned short* __restrict__ xbf,
        const float* __restrict__ wgate, const float* __restrict__ wup,
        const float* __restrict__ swgate, const float* __restrict__ swup,
        const int* __restrict__ list, const int* __restrict__ cnt,
        unsigned short* __restrict__ h) {
    int bx = blockIdx.x;
    int ve, start, end;
    if (bx < E) { ve = bx; start = 0; end = cnt[ve]; }
    else        { ve = E; start = (bx - E) * 256; end = start + 256; }
    if (start >= end) return;
    const int i0 = blockIdx.y * 32;
    const int tid = threadIdx.x, wave = tid >> 6, lane = tid & 63;
    const int lcol = lane & 15, lkg = lane >> 4;
    const int mat = tid >> 7;
    const int wcq = tid & 7;
    const int wkq = (tid >> 3) & 15;
    const float* G = (ve < E) ? wgate + (size_t)ve * H * II : swgate;
    const float* U = (ve < E) ? wup   + (size_t)ve * H * II : swup;
    const float* Wsrc = (mat ? U : G) + (size_t)(wkq * 4) * II + i0 + wcq * 4;
    __shared__ unsigned short lB[2][2][32 * 64];   // [buf][mat][row i][k]
    __shared__ int tokL[256];
    const int slotbase = (ve < E) ? ve * CAPH : E * CAPH;

#define STAGE_A(BUF) { \
        char* dst = (char*)&lB[BUF][mat][0]; \
        _Pragma("unroll") \
        for (int c = 0; c < 4; ++c) { \
            int ii = wcq * 4 + c; \
            unsigned int ad = ((unsigned)ii * 128 + (unsigned)wkq * 8) ^ (((unsigned)(ii & 7)) << 4); \
            u32x2 pk; \
            pk[0] = cvtpk(pf[0][c], pf[1][c]); \
            pk[1] = cvtpk(pf[2][c], pf[3][c]); \
            *reinterpret_cast<u32x2*>(dst + ad) = pk; \
        } }

    for (int m0 = start; m0 < end; m0 += 256) {
        int msize = min(256, end - m0);
        tokL[tid] = (tid < msize) ? list[ve * CAP + m0 + tid] : 0;
        f32x4 accg[4][2] = {};
        f32x4 accu[4][2] = {};
        f32x4 pf[4];
        #pragma unroll
        for (int q = 0; q < 4; ++q)
            pf[q] = *reinterpret_cast<const f32x4*>(Wsrc + (size_t)q * II);
        STAGE_A(0)
        __syncthreads();
        const unsigned short* xrow[4];
        #pragma unroll
        for (int m = 0; m < 4; ++m)
            xrow[m] = xbf + (size_t)tokL[wave * 64 + m * 16 + lcol] * H;
        bool wact = (wave * 64) < msize;

        for (int ks = 0; ks < 32; ++ks) {
            const int cur = ks & 1;
            const int k0 = ks * 64;
            // (1) a-gathers for THIS k-step — issued first
            short8 a[2][4];
            if (wact) {
                #pragma unroll
                for (int s = 0; s < 2; ++s)
                    #pragma unroll
                    for (int m = 0; m < 4; ++m)
                        a[s][m] = *reinterpret_cast<const short8*>(&xrow[m][k0 + s * 32 + lkg * 8]);
            }
            __builtin_amdgcn_sched_barrier(0);
            // (2) weight prefetch for NEXT k-step — stays in flight through compute
            if (ks + 1 < 32) {
                const float* src = Wsrc + (size_t)((ks + 1) * 64) * II;
                #pragma unroll
                for (int q = 0; q < 4; ++q)
                    pf[q] = *reinterpret_cast<const f32x4*>(src + (size_t)q * II);
            }
            __builtin_amdgcn_sched_barrier(0);
            // (3) compute from a-regs + LDS(cur)
            if (wact) {
                const char* b0 = (const char*)&lB[cur][0][0];
                const char* b1 = (const char*)&lB[cur][1][0];
                #pragma unroll
                for (int s = 0; s < 2; ++s) {
                    #pragma unroll
                    for (int n = 0; n < 2; ++n) {
                        unsigned int ra = ((unsigned)(n * 16 + lcol) * 128 + (unsigned)(s * 64 + lkg * 16))
                                        ^ (((unsigned)(lcol & 7)) << 4);
                        const short8 bg = *reinterpret_cast<const short8*>(b0 + ra);
                        const short8 bu = *reinterpret_cast<const short8*>(b1 + ra);
                        #pragma unroll
                        for (int m = 0; m < 4; ++m) {
                            accg[m][n] = __builtin_amdgcn_mfma_f32_16x16x32_bf16(a[s][m], bg, accg[m][n], 0, 0, 0);
                            accu[m][n] = __builtin_amdgcn_mfma_f32_16x16x32_bf16(a[s][m], bu, accu[m][n], 0, 0, 0);
                        }
                    }
                }
            }
            // (4) stage next tile (vmcnt(0) waits only the pf loads)
            if (ks + 1 < 32) STAGE_A(cur ^ 1)
            __syncthreads();
        }
        if (wact) {
            #pragma unroll
            for (int m = 0; m < 4; ++m)
                #pragma unroll
                for (int n = 0; n < 2; ++n)
                    #pragma unroll
                    for (int r = 0; r < 4; ++r) {
                        int rowl = wave * 64 + m * 16 + lkg * 4 + r;
                        int pos = m0 + rowl;
                        bool ok = (rowl < msize) && !(ve < E && pos >= CAPH);
                        float gv = accg[m][n][r], uv = accu[m][n][r];
                        float hv = gv / (1.f + expf(-gv)) * uv;
                        if (ok)
                            h[(size_t)(slotbase + pos) * II + i0 + n * 16 + lcol] = f2bf(hv);
                    }
        }
        __syncthreads();
    }
#undef STAGE_A
}

// Pass B: out[tok] += wt * (h @ Wdown). Same ordering discipline.
__global__ __launch_bounds__(256, 3) void passB_kernel(
        const unsigned short* __restrict__ h,
        const float* __restrict__ wdown, const float* __restrict__ swdown,
        const int* __restrict__ list, const float* __restrict__ wts,
        const int* __restrict__ cnt, float* __restrict__ out) {
    int bx = blockIdx.x;
    int ve, start, end;
    if (bx < E) { ve = bx; start = 0; end = cnt[ve]; }
    else        { ve = E; start = (bx - E) * 256; end = start + 256; }
    if (start >= end) return;
    const float* W = (ve < E) ? wdown + (size_t)ve * II * H : swdown;
    const int n0 = blockIdx.y * 64;
    const int tid = threadIdx.x, wave = tid >> 6, lane = tid & 63;
    const int lcol = lane & 15, lkg = lane >> 4;
    const int wnq = tid & 15;
    const int wkq = tid >> 4;
    const float* Wsrc = W + (size_t)(wkq * 4) * H + n0 + wnq * 4;
    __shared__ unsigned short lW[2][64 * 64];
    __shared__ int tokL[256];
    __shared__ float wtL[256];
    const int slotbase = (ve < E) ? ve * CAPH : E * CAPH;
    const int NS = II / 64;  // 22

#define STAGE_B(BUF) { \
        char* dst = (char*)&lW[BUF][0]; \
        _Pragma("unroll") \
        for (int c = 0; c < 4; ++c) { \
            int nn = wnq * 4 + c; \
            unsigned int ad = ((unsigned)nn * 128 + (unsigned)wkq * 8) ^ (((unsigned)(nn & 7)) << 4); \
            u32x2 pk; \
            pk[0] = cvtpk(pf[0][c], pf[1][c]); \
            pk[1] = cvtpk(pf[2][c], pf[3][c]); \
            *reinterpret_cast<u32x2*>(dst + ad) = pk; \
        } }

    for (int m0 = start; m0 < end; m0 += 256) {
        int msize = min(256, end - m0);
        tokL[tid] = (tid < msize) ? list[ve * CAP + m0 + tid] : 0;
        wtL[tid]  = (tid < msize) ? wts[ve * CAP + m0 + tid] : 0.f;
        f32x4 acc[4][4] = {};
        f32x4 pf[4];
        #pragma unroll
        for (int q = 0; q < 4; ++q)
            pf[q] = *reinterpret_cast<const f32x4*>(Wsrc + (size_t)q * H);
        STAGE_B(0)
        __syncthreads();
        const unsigned short* hrow[4];
        #pragma unroll
        for (int m = 0; m < 4; ++m)
            hrow[m] = h + (size_t)(slotbase + m0 + wave * 64 + m * 16 + lcol) * II;
        bool wact = (wave * 64) < msize;

        for (int ks = 0; ks < NS; ++ks) {
            const int cur = ks & 1;
            const int k0 = ks * 64;
            short8 a[2][4];
            if (wact) {
                #pragma unroll
                for (int s = 0; s < 2; ++s)
                    #pragma unroll
                    for (int m = 0; m < 4; ++m)
                        a[s][m] = *reinterpret_cast<const short8*>(&hrow[m][k0 + s * 32 + lkg * 8]);
            }
            __builtin_amdgcn_sched_barrier(0);
            if (ks + 1 < NS) {
                const float* src = Wsrc + (size_t)((ks + 1) * 64) * H;
                #pragma unroll
                for (int q = 0; q < 4; ++q)
                    pf[q] = *reinterpret_cast<const f32x4*>(src + (size_t)q * H);
            }
            __builtin_amdgcn_sched_barrier(0);
            if (wact) {
                const char* bw0 = (const char*)&lW[cur][0];
                #pragma unroll
                for (int s = 0; s < 2; ++s) {
                    #pragma unroll
                    for (int n = 0; n < 4; ++n) {
                        unsigned int ra = ((unsigned)(n * 16 + lcol) * 128 + (unsigned)(s * 64 + lkg * 16))
                                        ^ (((unsigned)(lcol & 7)) << 4);
                        const short8 b = *reinterpret_cast<const short8*>(bw0 + ra);
                        #pragma unroll
                        for (int m = 0; m < 4; ++m)
                            acc[m][n] = __builtin_amdgcn_mfma_f32_16x16x32_bf16(a[s][m], b, acc[m][n], 0, 0, 0);
                    }
                }
            }
            if (ks + 1 < NS) STAGE_B(cur ^ 1)
            __syncthreads();
        }
        if (wact) {
            #pragma unroll
            for (int m = 0; m < 4; ++m)
                #pragma unroll
                for (int n = 0; n < 4; ++n)
                    #pragma unroll
                    for (int r = 0; r < 4; ++r) {
                        int rowl = wave * 64 + m * 16 + lkg * 4 + r;
                        if (rowl < msize) {
                            int tok = tokL[rowl];
                            float wv = wtL[rowl];
                            unsafeAtomicAdd(&out[(size_t)tok * H + n0 + n * 16 + lcol],
                                            acc[m][n][r] * wv);
                        }
                    }
        }
        __syncthreads();
    }
#undef STAGE_B
}

extern "C" void kernel_launch(void* const* d_in, const int* in_sizes, int n_in,
                              void* d_out, int out_size, void* d_ws, size_t ws_size,
                              hipStream_t stream) {
    const float* x       = (const float*)d_in[0];
    const float* gate_w  = (const float*)d_in[1];
    const float* e_bias  = (const float*)d_in[2];
    const float* w_gate  = (const float*)d_in[3];
    const float* w_up    = (const float*)d_in[4];
    const float* w_down  = (const float*)d_in[5];
    const float* sw_gate = (const float*)d_in[6];
    const float* sw_up   = (const float*)d_in[7];
    const float* sw_down = (const float*)d_in[8];
    float* out = (float*)d_out;

    char* ws = (char*)d_ws;
    unsigned short* xbf = (unsigned short*)ws;                       // 4 MB
    int*   list = (int*)(ws + 4194304);                              // 132 KB
    float* wts  = (float*)(ws + 4194304 + 135168);                   // 132 KB
    int*   cnt  = (int*)(ws + 4194304 + 2 * 135168);                 // 256 B
    unsigned short* h = (unsigned short*)(ws + 4194304 + 2 * 135168 + 256); // ~37.5 MB

    hipMemsetAsync(d_out, 0, (size_t)T * H * sizeof(float), stream);
    prep_kernel<<<dim3(2048), dim3(256), 0, stream>>>(x, xbf, list, wts, cnt);
    router_kernel<<<dim3(T), dim3(256), 0, stream>>>(x, gate_w, e_bias, list, wts, cnt);
    passA_kernel<<<dim3(36, 44), dim3(256), 0, stream>>>(xbf, w_gate, w_up, sw_gate, sw_up, list, cnt, h);
    passB_kernel<<<dim3(36, 32), dim3(256), 0, stream>>>(h, w_down, sw_down, list, wts, cnt, out);
}